// Round 9
// baseline (1454.672 us; speedup 1.0000x reference)
//
#include <hip/hip_runtime.h>
#include <hip/hip_bf16.h>
#include <math.h>

#define B_   64
#define T_   512
#define F_   256
#define ENC_ 256
#define P_   128
#define H_   256
#define K_   12
#define INV_TEMP 10.0f

typedef unsigned short u16;
typedef _Float16 half2v __attribute__((ext_vector_type(2)));
union U2H { unsigned int u; half2v h; };
typedef __attribute__((ext_vector_type(8))) short bf16x8;   // 8 bf16 = 4 VGPRs
typedef __attribute__((ext_vector_type(4))) float f32x4;    // MFMA C/D
union BF8 { bf16x8 v; u16 e[8]; };

// ---------------- helpers ----------------------------------------------------
__device__ __forceinline__ float dot2f16(unsigned int a, unsigned int b, float c) {
    U2H ua; ua.u = a; U2H ub; ub.u = b;
#if __has_builtin(__builtin_amdgcn_fdot2)
    return __builtin_amdgcn_fdot2(ua.h, ub.h, c, false);
#else
    return fmaf((float)ua.h.x, (float)ub.h.x, fmaf((float)ua.h.y, (float)ub.h.y, c));
#endif
}
__device__ __forceinline__ float rcpf(float x) {
#if __has_builtin(__builtin_amdgcn_rcpf)
    return __builtin_amdgcn_rcpf(x);
#else
    return 1.f / x;
#endif
}
__device__ __forceinline__ u16 f2bf(float f) {   // RNE
    unsigned int u = __float_as_uint(f);
    unsigned int r = (u + 0x7fffu + ((u >> 16) & 1u)) >> 16;
    return (u16)r;
}
__device__ __forceinline__ float bf2f(u16 v) {
    return __uint_as_float(((unsigned int)v) << 16);
}
__device__ __forceinline__ float wave_sum(float v) {
    #pragma unroll
    for (int o = 32; o > 0; o >>= 1) v += __shfl_down(v, o, 64);
    return v;
}

// ---------------- fold: Wct[p][f] = bf16((W_enc@W_proj)[f][p]); bc; accum=0 --
__global__ void fold_kernel(const float* __restrict__ We, const float* __restrict__ be,
                            const float* __restrict__ Wp, const float* __restrict__ bp,
                            u16* __restrict__ Wct, float* __restrict__ bc,
                            float* __restrict__ accum) {
    int f = blockIdx.x;      // 0..255 weight rows; 256 bias; 257 accum-zero
    int p = threadIdx.x;     // 0..127
    if (f < F_) {
        float a = 0.f;
        for (int e = 0; e < ENC_; e++) a = fmaf(We[f * ENC_ + e], Wp[e * P_ + p], a);
        Wct[(size_t)p * F_ + f] = f2bf(a);
    } else if (f == F_) {
        float a = bp[p];
        for (int e = 0; e < ENC_; e++) a = fmaf(be[e], Wp[e * P_ + p], a);
        bc[p] = a;
    } else {
        #pragma unroll
        for (int i = 0; i < 8; i++) accum[p * 8 + i] = 0.f;
    }
}

// ---------------- merged weight conversions ----------------------------------
// blocks 0..191: Wh -> packed f16 Whh; 192..287: Wi -> Wit bf16 (transposed);
// 288..671: Wp -> Wpt bf16 (transposed per k)
__global__ __launch_bounds__(256) void setup_conv(const float* __restrict__ Wh,
                                                  uint2* __restrict__ Whh,
                                                  const float* __restrict__ Wi,
                                                  u16* __restrict__ Wit,
                                                  const float* __restrict__ Wp,
                                                  u16* __restrict__ Wpt) {
    int bid = blockIdx.x;
    if (bid < 192) {
        int idx = bid * 256 + threadIdx.x;        // 49152 total
        int i4 = idx / 768, j = idx % 768;
        U2H lo, hi;
        lo.h.x = (_Float16)Wh[(size_t)(4 * i4 + 0) * 768 + j];
        lo.h.y = (_Float16)Wh[(size_t)(4 * i4 + 1) * 768 + j];
        hi.h.x = (_Float16)Wh[(size_t)(4 * i4 + 2) * 768 + j];
        hi.h.y = (_Float16)Wh[(size_t)(4 * i4 + 3) * 768 + j];
        Whh[idx] = make_uint2(lo.u, hi.u);
    } else if (bid < 288) {
        __shared__ float tile[32][33];
        int b2 = bid - 192;                       // 0..95
        int n0 = (b2 % 24) * 32, k0 = (b2 / 24) * 32;
        int tx = threadIdx.x & 31, ty = threadIdx.x >> 5;
        #pragma unroll
        for (int i = 0; i < 32; i += 8)
            tile[ty + i][tx] = Wi[(size_t)(k0 + ty + i) * 768 + n0 + tx];
        __syncthreads();
        #pragma unroll
        for (int i = 0; i < 32; i += 8)
            Wit[(size_t)(n0 + ty + i) * 128 + k0 + tx] = f2bf(tile[tx][ty + i]);
    } else {
        __shared__ float tile2[32][33];
        int b3 = bid - 288;                       // 0..383
        int kq = b3 / 32, rem = b3 % 32;
        int h0 = (rem % 8) * 32, p0 = (rem / 8) * 32;
        int tx = threadIdx.x & 31, ty = threadIdx.x >> 5;
        #pragma unroll
        for (int i = 0; i < 32; i += 8)
            tile2[ty + i][tx] = Wp[(size_t)kq * H_ * P_ + (size_t)(h0 + ty + i) * P_ + p0 + tx];
        __syncthreads();
        #pragma unroll
        for (int i = 0; i < 32; i += 8)
            Wpt[(size_t)kq * P_ * H_ + (size_t)(p0 + ty + i) * H_ + h0 + tx] = f2bf(tile2[tx][ty + i]);
    }
}

// ---------------- MFMA GEMM, A = fp32 (converted in-register) ----------------
// C(MxN,bf16) = bf16( A(MxK,f32) @ Bt(NxK,bf16)^T + bias ).  Block 64x128, 4 waves.
__global__ __launch_bounds__(256) void gemm_mfma_f32a(const float* __restrict__ A,
                                                      const u16* __restrict__ Bt,
                                                      const float* __restrict__ bias,
                                                      u16* __restrict__ Ch,
                                                      int N, int K) {
    int tid  = threadIdx.x;
    int w    = tid >> 6;
    int lane = tid & 63;
    int col  = lane & 15;
    int quad = lane >> 4;
    int bm = blockIdx.y * 64, bn = blockIdx.x * 128;

    f32x4 acc[8] = {};
    const float* arow = A + (size_t)(bm + w * 16 + col) * K;
    #pragma unroll
    for (int k0 = 0; k0 < K; k0 += 32) {
        float4 v0 = *(const float4*)(arow + k0 + quad * 8);
        float4 v1 = *(const float4*)(arow + k0 + quad * 8 + 4);
        BF8 af;
        af.e[0] = f2bf(v0.x); af.e[1] = f2bf(v0.y); af.e[2] = f2bf(v0.z); af.e[3] = f2bf(v0.w);
        af.e[4] = f2bf(v1.x); af.e[5] = f2bf(v1.y); af.e[6] = f2bf(v1.z); af.e[7] = f2bf(v1.w);
        #pragma unroll
        for (int nt = 0; nt < 8; nt++) {
            bf16x8 bf = *(const bf16x8*)(Bt + (size_t)(bn + nt * 16 + col) * K + k0 + quad * 8);
            acc[nt] = __builtin_amdgcn_mfma_f32_16x16x32_bf16(af.v, bf, acc[nt], 0, 0, 0);
        }
    }
    #pragma unroll
    for (int nt = 0; nt < 8; nt++) {
        int gn = bn + nt * 16 + col;
        float bv = bias[gn];
        #pragma unroll
        for (int r = 0; r < 4; r++) {
            int gm = bm + w * 16 + quad * 4 + r;
            Ch[(size_t)gm * N + gn] = f2bf(acc[nt][r] + bv);
        }
    }
}

// ---------------- MFMA GEMM, A = bf16, C = bf16 ------------------------------
__global__ __launch_bounds__(256) void gemm_mfma(const u16* __restrict__ A,
                                                 const u16* __restrict__ Bt,
                                                 const float* __restrict__ bias,
                                                 u16* __restrict__ Ch,
                                                 int N, int K) {
    int tid  = threadIdx.x;
    int w    = tid >> 6;
    int lane = tid & 63;
    int col  = lane & 15;
    int quad = lane >> 4;
    int bm = blockIdx.y * 64, bn = blockIdx.x * 128;

    f32x4 acc[8] = {};
    const u16* arow = A + (size_t)(bm + w * 16 + col) * K;
    #pragma unroll
    for (int k0 = 0; k0 < K; k0 += 32) {
        bf16x8 af = *(const bf16x8*)(arow + k0 + quad * 8);
        #pragma unroll
        for (int nt = 0; nt < 8; nt++) {
            bf16x8 bf = *(const bf16x8*)(Bt + (size_t)(bn + nt * 16 + col) * K + k0 + quad * 8);
            acc[nt] = __builtin_amdgcn_mfma_f32_16x16x32_bf16(af, bf, acc[nt], 0, 0, 0);
        }
    }
    #pragma unroll
    for (int nt = 0; nt < 8; nt++) {
        int gn = bn + nt * 16 + col;
        float bv = bias[gn];
        #pragma unroll
        for (int r = 0; r < 4; r++) {
            int gm = bm + w * 16 + quad * 4 + r;
            Ch[(size_t)gm * N + gn] = f2bf(acc[nt][r] + bv);
        }
    }
}

// ---------------- suffix sums of z: zsuf[b][k-1][p] = sum_{t>=k} z[b][t][p] --
__global__ void zsuf_kernel(const u16* __restrict__ zh, float* __restrict__ zsuf) {
    int b = blockIdx.x;
    int p = threadIdx.x;          // 0..127
    const u16* zb = zh + (size_t)b * T_ * P_ + p;
    float s = 0.f;
    for (int t = T_ - 1; t >= 1; t--) {
        s += bf2f(zb[(size_t)t * P_]);
        if (t <= K_) zsuf[((size_t)b * K_ + (t - 1)) * P_ + p] = s;
    }
}

// ---------------- GRU scan (gi in bf16; float4-packed partials) --------------
__global__ __attribute__((amdgpu_flat_work_group_size(512, 512), amdgpu_waves_per_eu(2, 2)))
void gru_kernel(const u16* __restrict__ gi,
                const uint2* __restrict__ Whh,
                const float* __restrict__ bhn,
                u16* __restrict__ ch) {
    int b    = blockIdx.x;
    int tid  = threadIdx.x;          // 0..511
    int j    = tid & 255;
    int half = tid >> 8;
    __shared__ _Float16 hbuf[H_];
    __shared__ float4 ps[2][256];

    uint2 wR[32], wZ[32], wN[32];
    {
        const uint2* base = Whh + (size_t)(half * 32) * 768;
        const uint2* cR = base + j;
        const uint2* cZ = base + 256 + j;
        const uint2* cN = base + 512 + j;
        #pragma unroll
        for (int i = 0; i < 32; i++) {
            wR[i] = cR[(size_t)i * 768];
            wZ[i] = cZ[(size_t)i * 768];
            wN[i] = cN[(size_t)i * 768];
        }
        #pragma unroll
        for (int i = 0; i < 32; i++) {
            asm volatile("" : "+v"(wR[i].x), "+v"(wR[i].y));
            asm volatile("" : "+v"(wZ[i].x), "+v"(wZ[i].y));
            asm volatile("" : "+v"(wN[i].x), "+v"(wN[i].y));
        }
    }
    if (tid < H_) hbuf[tid] = (_Float16)0.f;
    float bh = bhn[j];
    float hloc = 0.f;

    const u16* gib = gi + (size_t)b * T_ * 768;
    u16* cb = ch + (size_t)b * T_ * H_;
    float ir = 0.f, iz = 0.f, inn = 0.f;
    if (tid < 256) { ir = bf2f(gib[j]); iz = bf2f(gib[256 + j]); inn = bf2f(gib[512 + j]); }
    __syncthreads();

    const uint2* hw = (const uint2*)hbuf;
    #pragma unroll 1
    for (int t = 0; t < T_; t++) {
        float nir = 0.f, niz = 0.f, ninn = 0.f;
        if (tid < 256) {
            int tn = (t + 1 < T_) ? t + 1 : t;
            const u16* gtn = gib + (size_t)tn * 768;
            nir = bf2f(gtn[j]); niz = bf2f(gtn[256 + j]); ninn = bf2f(gtn[512 + j]);
        }
        float ar0 = 0.f, ar1 = 0.f, az0 = 0.f, az1 = 0.f, an0 = 0.f, an1 = 0.f;
        #pragma unroll
        for (int i = 0; i < 32; i++) {
            uint2 hv = hw[half * 32 + i];
            ar0 = dot2f16(hv.x, wR[i].x, ar0);
            ar1 = dot2f16(hv.y, wR[i].y, ar1);
            az0 = dot2f16(hv.x, wZ[i].x, az0);
            az1 = dot2f16(hv.y, wZ[i].y, az1);
            an0 = dot2f16(hv.x, wN[i].x, an0);
            an1 = dot2f16(hv.y, wN[i].y, an1);
        }
        ps[half][j] = make_float4(ar0 + ar1, az0 + az1, an0 + an1, 0.f);
        __syncthreads();
        if (tid < 256) {
            float4 p0 = ps[0][j], p1 = ps[1][j];
            float ar = p0.x + p1.x;
            float az = p0.y + p1.y;
            float an = p0.z + p1.z;
            float r   = rcpf(1.f + __expf(-(ir + ar)));
            float zg  = rcpf(1.f + __expf(-(iz + az)));
            float xn  = inn + r * (an + bh);
            float n   = fmaf(2.f, rcpf(1.f + __expf(-2.f * xn)), -1.f);
            hloc = (1.f - zg) * n + zg * hloc;
            cb[(size_t)t * H_ + j] = f2bf(hloc);
            hbuf[j] = (_Float16)hloc;
        }
        ir = nir; iz = niz; inn = ninn;
        __syncthreads();
    }
}

// ---------------- fused loss, MFMA; mean-logit via suffix-sum dot ------------
__global__ __launch_bounds__(256) void loss_fused(const u16* __restrict__ ch,
                                                  const u16* __restrict__ Wpt,
                                                  const float* __restrict__ bp,
                                                  const u16* __restrict__ zh,
                                                  const float* __restrict__ zsuf,
                                                  float* __restrict__ accum) {
    __shared__ u16 Pst[64][136];
    __shared__ float sS[128];
    __shared__ float red[4];
    int k  = blockIdx.z + 1;
    int b  = blockIdx.y;
    int t0 = blockIdx.x * 64;
    int Tk = T_ - k;
    int tid  = threadIdx.x;
    int w    = tid >> 6;
    int lane = tid & 63;
    int col  = lane & 15;
    int quad = lane >> 4;

    if (tid < 128) sS[tid] = zsuf[((size_t)b * K_ + (k - 1)) * P_ + tid];

    // ---- phase 1: Pst = bf16(ch-tile @ Wp[k] + bp[k]) -----------------------
    {
        f32x4 acc[8] = {};
        const u16* arow = ch + ((size_t)b * T_ + t0 + w * 16 + col) * H_;
        const u16* wk   = Wpt + (size_t)(k - 1) * P_ * H_;
        #pragma unroll
        for (int k0 = 0; k0 < 8; k0++) {
            bf16x8 af = *(const bf16x8*)(arow + k0 * 32 + quad * 8);
            #pragma unroll
            for (int nt = 0; nt < 8; nt++) {
                bf16x8 bf = *(const bf16x8*)(wk + (size_t)(nt * 16 + col) * H_ + k0 * 32 + quad * 8);
                acc[nt] = __builtin_amdgcn_mfma_f32_16x16x32_bf16(af, bf, acc[nt], 0, 0, 0);
            }
        }
        #pragma unroll
        for (int nt = 0; nt < 8; nt++) {
            float bias = bp[(size_t)(k - 1) * P_ + nt * 16 + col];
            #pragma unroll
            for (int r = 0; r < 4; r++)
                Pst[w * 16 + quad * 4 + r][nt * 16 + col] = f2bf(acc[nt][r] + bias);
        }
    }
    __syncthreads();

    // ---- phase 2: flash LSE (no mean-logit accumulation) --------------------
    float mloc[4], sloc[4];
    #pragma unroll
    for (int r = 0; r < 4; r++) { mloc[r] = -INFINITY; sloc[r] = 0.f; }
    const u16* zb = zh + (size_t)b * T_ * P_;

    for (int ct = 0; ct < Tk; ct += 64) {
        f32x4 acc[4] = {};
        #pragma unroll
        for (int k0 = 0; k0 < 4; k0++) {
            bf16x8 af = *(const bf16x8*)(&Pst[w * 16 + col][k0 * 32 + quad * 8]);
            #pragma unroll
            for (int nt = 0; nt < 4; nt++) {
                int tcol = k + ct + nt * 16 + col;   // may over-read into zsuf region (masked)
                bf16x8 bf = *(const bf16x8*)(zb + (size_t)tcol * P_ + k0 * 32 + quad * 8);
                acc[nt] = __builtin_amdgcn_mfma_f32_16x16x32_bf16(af, bf, acc[nt], 0, 0, 0);
            }
        }
        #pragma unroll
        for (int r = 0; r < 4; r++) {
            float l[4];
            float tmax = -INFINITY;
            #pragma unroll
            for (int nt = 0; nt < 4; nt++) {
                bool valid = (ct + nt * 16 + col) < Tk;
                l[nt] = valid ? acc[nt][r] * INV_TEMP : -INFINITY;
                tmax = fmaxf(tmax, l[nt]);
            }
            float mnew = fmaxf(mloc[r], tmax);
            float e = __expf(l[0] - mnew) + __expf(l[1] - mnew)
                    + __expf(l[2] - mnew) + __expf(l[3] - mnew);
            sloc[r] = sloc[r] * __expf(mloc[r] - mnew) + e;
            mloc[r] = mnew;
        }
    }
    #pragma unroll
    for (int r = 0; r < 4; r++) {
        #pragma unroll
        for (int o = 1; o < 16; o <<= 1) {
            float mo = __shfl_xor(mloc[r], o, 64);
            float so = __shfl_xor(sloc[r], o, 64);
            float mn = fmaxf(mloc[r], mo);
            sloc[r] = sloc[r] * __expf(mloc[r] - mn) + so * __expf(mo - mn);
            mloc[r] = mn;
        }
    }
    // mean(logits) per row = (INV_TEMP/Tk) * dot(Pst[row], S)
    float tkinv = INV_TEMP / (float)Tk;
    float scale = 1.0f / ((float)K_ * (float)B_ * (float)Tk);
    float bs = 0.f;
    #pragma unroll
    for (int r = 0; r < 4; r++) {
        int row = w * 16 + quad * 4 + r;
        BF8 pv;
        pv.v = *(const bf16x8*)(&Pst[row][col * 8]);
        float d = 0.f;
        #pragma unroll
        for (int m = 0; m < 8; m++) d = fmaf(bf2f(pv.e[m]), sS[col * 8 + m], d);
        #pragma unroll
        for (int o = 1; o < 16; o <<= 1) d += __shfl_xor(d, o, 64);
        int gr = t0 + row;
        if (gr < Tk) bs += mloc[r] + __logf(sloc[r]) - d * tkinv;
    }
    if (col != 0) bs = 0.f;
    bs = wave_sum(bs);
    if (lane == 0) red[w] = bs;
    __syncthreads();
    if (tid == 0)
        atomicAdd(&accum[(blockIdx.x * 809 + b * 67 + blockIdx.z * 131) & 1023],
                  (red[0] + red[1] + red[2] + red[3]) * scale);
}

__global__ void finalize(const float* __restrict__ accum, float* __restrict__ out) {
    int tid = threadIdx.x;
    __shared__ float red[4];
    float v = 0.f;
    for (int i = tid; i < 1024; i += 256) v += accum[i];
    float sres = wave_sum(v);
    if ((tid & 63) == 0) red[tid >> 6] = sres;
    __syncthreads();
    if (tid == 0) out[0] = red[0] + red[1] + red[2] + red[3];
}

// ---------------- launch -----------------------------------------------------
extern "C" void kernel_launch(void* const* d_in, const int* in_sizes, int n_in,
                              void* d_out, int out_size, void* d_ws, size_t ws_size,
                              hipStream_t stream) {
    const float* x      = (const float*)d_in[0];
    const float* W_enc  = (const float*)d_in[1];
    const float* b_enc  = (const float*)d_in[2];
    const float* W_proj = (const float*)d_in[3];
    const float* b_proj = (const float*)d_in[4];
    const float* Wi     = (const float*)d_in[5];
    const float* bi     = (const float*)d_in[6];
    const float* Wh     = (const float*)d_in[7];
    const float* bhn    = (const float*)d_in[8];
    const float* Wp     = (const float*)d_in[9];
    const float* bp     = (const float*)d_in[10];
    float* out = (float*)d_out;

    // layout (float offsets)
    float* ws    = (float*)d_ws;
    float* bc    = ws;                          // 128
    float* accum = bc + 128;                    // 1024 -> end 1152
    uint2* Whh   = (uint2*)(ws + 1152);         // 98304 fl -> end 99456
    u16* Wct     = (u16*)(ws + 99456);          // 16384 fl -> end 115840
    u16* Wit     = (u16*)(ws + 115840);         // 49152 fl -> end 164992
    u16* Wpt     = (u16*)(ws + 164992);         // 196608 fl -> end 361600
    u16* zh      = (u16*)(ws + 361600);         // 2097152 fl -> end 2458752
    float* zsuf  = ws + 2458752;                // 98304 fl (also zh over-read slack) -> end 2557056
    u16* gi      = (u16*)(ws + 2557056);        // 12582912 fl -> end 15139968
    u16* ch      = (u16*)(ws + 15139968);       // 4194304 fl -> end 19334272 (~77 MB)

    const int MT = B_ * T_;                     // 32768

    fold_kernel<<<F_ + 2, P_, 0, stream>>>(W_enc, b_enc, W_proj, b_proj, Wct, bc, accum);
    setup_conv<<<672, 256, 0, stream>>>(Wh, Whh, Wi, Wit, Wp, Wpt);
    // zh = bf16(x @ Wct^T + bc)   (M=32768, N=128, K=256; A converted in-reg)
    gemm_mfma_f32a<<<dim3(1, MT / 64), 256, 0, stream>>>(x, Wct, bc, zh, P_, F_);
    // gi = bf16(zh @ Wit^T + bi)  (M=32768, N=768, K=128)
    gemm_mfma<<<dim3(6, MT / 64), 256, 0, stream>>>(zh, Wit, bi, gi, 3 * H_, P_);
    // suffix sums of z for the mean-logit term
    zsuf_kernel<<<B_, P_, 0, stream>>>(zh, zsuf);
    // GRU scan -> ch (bf16)
    gru_kernel<<<B_, 512, 0, stream>>>(gi, Whh, bhn, ch);
    // fused pred-GEMM + flash loss (MFMA), all k in one dispatch
    loss_fused<<<dim3(8, B_, K_), 256, 0, stream>>>(ch, Wpt, bp, zh, zsuf, accum);
    finalize<<<1, 256, 0, stream>>>(accum, out);
}

// Round 10
// 1359.925 us; speedup vs baseline: 1.0697x; 1.0697x over previous
//
#include <hip/hip_runtime.h>
#include <hip/hip_bf16.h>
#include <math.h>

#define B_   64
#define T_   512
#define F_   256
#define ENC_ 256
#define P_   128
#define H_   256
#define K_   12
#define INV_TEMP 10.0f

typedef unsigned short u16;
typedef _Float16 half2v __attribute__((ext_vector_type(2)));
union U2H { unsigned int u; half2v h; };
typedef __attribute__((ext_vector_type(8))) short bf16x8;   // 8 bf16 = 4 VGPRs
typedef __attribute__((ext_vector_type(4))) float f32x4;    // MFMA C/D
union BF8 { bf16x8 v; u16 e[8]; };

// ---------------- helpers ----------------------------------------------------
__device__ __forceinline__ float dot2f16(unsigned int a, unsigned int b, float c) {
    U2H ua; ua.u = a; U2H ub; ub.u = b;
#if __has_builtin(__builtin_amdgcn_fdot2)
    return __builtin_amdgcn_fdot2(ua.h, ub.h, c, false);
#else
    return fmaf((float)ua.h.x, (float)ub.h.x, fmaf((float)ua.h.y, (float)ub.h.y, c));
#endif
}
__device__ __forceinline__ float rcpf(float x) {
#if __has_builtin(__builtin_amdgcn_rcpf)
    return __builtin_amdgcn_rcpf(x);
#else
    return 1.f / x;
#endif
}
__device__ __forceinline__ u16 f2bf(float f) {   // RNE
    unsigned int u = __float_as_uint(f);
    unsigned int r = (u + 0x7fffu + ((u >> 16) & 1u)) >> 16;
    return (u16)r;
}
__device__ __forceinline__ float bf2f(u16 v) {
    return __uint_as_float(((unsigned int)v) << 16);
}
__device__ __forceinline__ float bflo(unsigned int u) { return __uint_as_float(u << 16); }
__device__ __forceinline__ float bfhi(unsigned int u) { return __uint_as_float(u & 0xffff0000u); }
__device__ __forceinline__ float wave_sum(float v) {
    #pragma unroll
    for (int o = 32; o > 0; o >>= 1) v += __shfl_down(v, o, 64);
    return v;
}

// ---------------- fold: Wct[p][f] = bf16((W_enc@W_proj)[f][p]); bc; accum=0 --
__global__ void fold_kernel(const float* __restrict__ We, const float* __restrict__ be,
                            const float* __restrict__ Wp, const float* __restrict__ bp,
                            u16* __restrict__ Wct, float* __restrict__ bc,
                            float* __restrict__ accum) {
    int f = blockIdx.x;      // 0..255 weight rows; 256 bias; 257 accum-zero
    int p = threadIdx.x;     // 0..127
    if (f < F_) {
        float a = 0.f;
        for (int e = 0; e < ENC_; e++) a = fmaf(We[f * ENC_ + e], Wp[e * P_ + p], a);
        Wct[(size_t)p * F_ + f] = f2bf(a);
    } else if (f == F_) {
        float a = bp[p];
        for (int e = 0; e < ENC_; e++) a = fmaf(be[e], Wp[e * P_ + p], a);
        bc[p] = a;
    } else {
        #pragma unroll
        for (int i = 0; i < 8; i++) accum[p * 8 + i] = 0.f;
    }
}

// ---------------- merged weight conversions ----------------------------------
__global__ __launch_bounds__(256) void setup_conv(const float* __restrict__ Wh,
                                                  uint2* __restrict__ Whh,
                                                  const float* __restrict__ Wi,
                                                  u16* __restrict__ Wit,
                                                  const float* __restrict__ Wp,
                                                  u16* __restrict__ Wpt) {
    int bid = blockIdx.x;
    if (bid < 192) {
        int idx = bid * 256 + threadIdx.x;        // 49152 total
        int i4 = idx / 768, j = idx % 768;
        U2H lo, hi;
        lo.h.x = (_Float16)Wh[(size_t)(4 * i4 + 0) * 768 + j];
        lo.h.y = (_Float16)Wh[(size_t)(4 * i4 + 1) * 768 + j];
        hi.h.x = (_Float16)Wh[(size_t)(4 * i4 + 2) * 768 + j];
        hi.h.y = (_Float16)Wh[(size_t)(4 * i4 + 3) * 768 + j];
        Whh[idx] = make_uint2(lo.u, hi.u);
    } else if (bid < 288) {
        __shared__ float tile[32][33];
        int b2 = bid - 192;                       // 0..95
        int n0 = (b2 % 24) * 32, k0 = (b2 / 24) * 32;
        int tx = threadIdx.x & 31, ty = threadIdx.x >> 5;
        #pragma unroll
        for (int i = 0; i < 32; i += 8)
            tile[ty + i][tx] = Wi[(size_t)(k0 + ty + i) * 768 + n0 + tx];
        __syncthreads();
        #pragma unroll
        for (int i = 0; i < 32; i += 8)
            Wit[(size_t)(n0 + ty + i) * 128 + k0 + tx] = f2bf(tile[tx][ty + i]);
    } else {
        __shared__ float tile2[32][33];
        int b3 = bid - 288;                       // 0..383
        int kq = b3 / 32, rem = b3 % 32;
        int h0 = (rem % 8) * 32, p0 = (rem / 8) * 32;
        int tx = threadIdx.x & 31, ty = threadIdx.x >> 5;
        #pragma unroll
        for (int i = 0; i < 32; i += 8)
            tile2[ty + i][tx] = Wp[(size_t)kq * H_ * P_ + (size_t)(h0 + ty + i) * P_ + p0 + tx];
        __syncthreads();
        #pragma unroll
        for (int i = 0; i < 32; i += 8)
            Wpt[(size_t)kq * P_ * H_ + (size_t)(p0 + ty + i) * H_ + h0 + tx] = f2bf(tile2[tx][ty + i]);
    }
}

// ---------------- MFMA GEMM, A = fp32 (converted in-register) ----------------
__global__ __launch_bounds__(256) void gemm_mfma_f32a(const float* __restrict__ A,
                                                      const u16* __restrict__ Bt,
                                                      const float* __restrict__ bias,
                                                      u16* __restrict__ Ch,
                                                      int N, int K) {
    int tid  = threadIdx.x;
    int w    = tid >> 6;
    int lane = tid & 63;
    int col  = lane & 15;
    int quad = lane >> 4;
    int bm = blockIdx.y * 64, bn = blockIdx.x * 128;

    f32x4 acc[8] = {};
    const float* arow = A + (size_t)(bm + w * 16 + col) * K;
    #pragma unroll
    for (int k0 = 0; k0 < K; k0 += 32) {
        float4 v0 = *(const float4*)(arow + k0 + quad * 8);
        float4 v1 = *(const float4*)(arow + k0 + quad * 8 + 4);
        BF8 af;
        af.e[0] = f2bf(v0.x); af.e[1] = f2bf(v0.y); af.e[2] = f2bf(v0.z); af.e[3] = f2bf(v0.w);
        af.e[4] = f2bf(v1.x); af.e[5] = f2bf(v1.y); af.e[6] = f2bf(v1.z); af.e[7] = f2bf(v1.w);
        #pragma unroll
        for (int nt = 0; nt < 8; nt++) {
            bf16x8 bf = *(const bf16x8*)(Bt + (size_t)(bn + nt * 16 + col) * K + k0 + quad * 8);
            acc[nt] = __builtin_amdgcn_mfma_f32_16x16x32_bf16(af.v, bf, acc[nt], 0, 0, 0);
        }
    }
    #pragma unroll
    for (int nt = 0; nt < 8; nt++) {
        int gn = bn + nt * 16 + col;
        float bv = bias[gn];
        #pragma unroll
        for (int r = 0; r < 4; r++) {
            int gm = bm + w * 16 + quad * 4 + r;
            Ch[(size_t)gm * N + gn] = f2bf(acc[nt][r] + bv);
        }
    }
}

// ---------------- MFMA GEMM, A = bf16, C = bf16 ------------------------------
__global__ __launch_bounds__(256) void gemm_mfma(const u16* __restrict__ A,
                                                 const u16* __restrict__ Bt,
                                                 const float* __restrict__ bias,
                                                 u16* __restrict__ Ch,
                                                 int N, int K) {
    int tid  = threadIdx.x;
    int w    = tid >> 6;
    int lane = tid & 63;
    int col  = lane & 15;
    int quad = lane >> 4;
    int bm = blockIdx.y * 64, bn = blockIdx.x * 128;

    f32x4 acc[8] = {};
    const u16* arow = A + (size_t)(bm + w * 16 + col) * K;
    #pragma unroll
    for (int k0 = 0; k0 < K; k0 += 32) {
        bf16x8 af = *(const bf16x8*)(arow + k0 + quad * 8);
        #pragma unroll
        for (int nt = 0; nt < 8; nt++) {
            bf16x8 bf = *(const bf16x8*)(Bt + (size_t)(bn + nt * 16 + col) * K + k0 + quad * 8);
            acc[nt] = __builtin_amdgcn_mfma_f32_16x16x32_bf16(af, bf, acc[nt], 0, 0, 0);
        }
    }
    #pragma unroll
    for (int nt = 0; nt < 8; nt++) {
        int gn = bn + nt * 16 + col;
        float bv = bias[gn];
        #pragma unroll
        for (int r = 0; r < 4; r++) {
            int gm = bm + w * 16 + quad * 4 + r;
            Ch[(size_t)gm * N + gn] = f2bf(acc[nt][r] + bv);
        }
    }
}

// ---------------- zsum[b][p] = sum_{t=1..T-1} z[b][t][p] (parallel 16-split) -
__global__ __launch_bounds__(512) void zsum_kernel(const u16* __restrict__ zh,
                                                   float* __restrict__ zsum) {
    int b   = blockIdx.x;
    int tid = threadIdx.x;
    int pg  = tid & 31;          // 32 groups of 4 consecutive p (uint2 = 4 bf16)
    int g   = tid >> 5;          // 16 t-strides
    __shared__ float part[16][128];
    const u16* zb = zh + (size_t)b * T_ * P_;
    float s0 = 0.f, s1 = 0.f, s2 = 0.f, s3 = 0.f;
    for (int t = 1 + g; t < T_; t += 16) {
        uint2 v = *(const uint2*)(zb + (size_t)t * P_ + pg * 4);
        s0 += bflo(v.x); s1 += bfhi(v.x);
        s2 += bflo(v.y); s3 += bfhi(v.y);
    }
    part[g][pg * 4 + 0] = s0; part[g][pg * 4 + 1] = s1;
    part[g][pg * 4 + 2] = s2; part[g][pg * 4 + 3] = s3;
    __syncthreads();
    if (tid < 128) {
        float s = 0.f;
        #pragma unroll
        for (int g2 = 0; g2 < 16; g2++) s += part[g2][tid];
        zsum[(size_t)b * P_ + tid] = s;
    }
}

// ---------------- GRU scan (gi in bf16; float4-packed partials) --------------
__global__ __attribute__((amdgpu_flat_work_group_size(512, 512), amdgpu_waves_per_eu(2, 2)))
void gru_kernel(const u16* __restrict__ gi,
                const uint2* __restrict__ Whh,
                const float* __restrict__ bhn,
                u16* __restrict__ ch) {
    int b    = blockIdx.x;
    int tid  = threadIdx.x;          // 0..511
    int j    = tid & 255;
    int half = tid >> 8;
    __shared__ _Float16 hbuf[H_];
    __shared__ float4 ps[2][256];

    uint2 wR[32], wZ[32], wN[32];
    {
        const uint2* base = Whh + (size_t)(half * 32) * 768;
        const uint2* cR = base + j;
        const uint2* cZ = base + 256 + j;
        const uint2* cN = base + 512 + j;
        #pragma unroll
        for (int i = 0; i < 32; i++) {
            wR[i] = cR[(size_t)i * 768];
            wZ[i] = cZ[(size_t)i * 768];
            wN[i] = cN[(size_t)i * 768];
        }
        #pragma unroll
        for (int i = 0; i < 32; i++) {
            asm volatile("" : "+v"(wR[i].x), "+v"(wR[i].y));
            asm volatile("" : "+v"(wZ[i].x), "+v"(wZ[i].y));
            asm volatile("" : "+v"(wN[i].x), "+v"(wN[i].y));
        }
    }
    if (tid < H_) hbuf[tid] = (_Float16)0.f;
    float bh = bhn[j];
    float hloc = 0.f;

    const u16* gib = gi + (size_t)b * T_ * 768;
    u16* cb = ch + (size_t)b * T_ * H_;
    float ir = 0.f, iz = 0.f, inn = 0.f;
    if (tid < 256) { ir = bf2f(gib[j]); iz = bf2f(gib[256 + j]); inn = bf2f(gib[512 + j]); }
    __syncthreads();

    const uint2* hw = (const uint2*)hbuf;
    #pragma unroll 1
    for (int t = 0; t < T_; t++) {
        float nir = 0.f, niz = 0.f, ninn = 0.f;
        if (tid < 256) {
            int tn = (t + 1 < T_) ? t + 1 : t;
            const u16* gtn = gib + (size_t)tn * 768;
            nir = bf2f(gtn[j]); niz = bf2f(gtn[256 + j]); ninn = bf2f(gtn[512 + j]);
        }
        float ar0 = 0.f, ar1 = 0.f, az0 = 0.f, az1 = 0.f, an0 = 0.f, an1 = 0.f;
        #pragma unroll
        for (int i = 0; i < 32; i++) {
            uint2 hv = hw[half * 32 + i];
            ar0 = dot2f16(hv.x, wR[i].x, ar0);
            ar1 = dot2f16(hv.y, wR[i].y, ar1);
            az0 = dot2f16(hv.x, wZ[i].x, az0);
            az1 = dot2f16(hv.y, wZ[i].y, az1);
            an0 = dot2f16(hv.x, wN[i].x, an0);
            an1 = dot2f16(hv.y, wN[i].y, an1);
        }
        ps[half][j] = make_float4(ar0 + ar1, az0 + az1, an0 + an1, 0.f);
        __syncthreads();
        if (tid < 256) {
            float4 p0 = ps[0][j], p1 = ps[1][j];
            float ar = p0.x + p1.x;
            float az = p0.y + p1.y;
            float an = p0.z + p1.z;
            float r   = rcpf(1.f + __expf(-(ir + ar)));
            float zg  = rcpf(1.f + __expf(-(iz + az)));
            float xn  = inn + r * (an + bh);
            float n   = fmaf(2.f, rcpf(1.f + __expf(-2.f * xn)), -1.f);
            hloc = (1.f - zg) * n + zg * hloc;
            cb[(size_t)t * H_ + j] = f2bf(hloc);
            hbuf[j] = (_Float16)hloc;
        }
        ir = nir; iz = niz; inn = ninn;
        __syncthreads();
    }
}

// ---------------- fused loss, MFMA; mean-logit via zsum + small correction ---
__global__ __launch_bounds__(256) void loss_fused(const u16* __restrict__ ch,
                                                  const u16* __restrict__ Wpt,
                                                  const float* __restrict__ bp,
                                                  const u16* __restrict__ zh,
                                                  const float* __restrict__ zsum,
                                                  float* __restrict__ accum) {
    __shared__ u16 Pst[64][136];
    __shared__ float sS[128];
    __shared__ float red[4];
    int k  = blockIdx.z + 1;
    int b  = blockIdx.y;
    int t0 = blockIdx.x * 64;
    int Tk = T_ - k;
    int tid  = threadIdx.x;
    int w    = tid >> 6;
    int lane = tid & 63;
    int col  = lane & 15;
    int quad = lane >> 4;
    const u16* zb = zh + (size_t)b * T_ * P_;

    // S_bk = zsum_b - sum_{t=1}^{k-1} z[t]   (<= 11 coalesced rows, one-time)
    if (tid < 128) {
        float s = zsum[(size_t)b * P_ + tid];
        for (int t = 1; t < k; t++) s -= bf2f(zb[(size_t)t * P_ + tid]);
        sS[tid] = s;
    }

    // ---- phase 1: Pst = bf16(ch-tile @ Wp[k] + bp[k]) -----------------------
    {
        f32x4 acc[8] = {};
        const u16* arow = ch + ((size_t)b * T_ + t0 + w * 16 + col) * H_;
        const u16* wk   = Wpt + (size_t)(k - 1) * P_ * H_;
        #pragma unroll
        for (int k0 = 0; k0 < 8; k0++) {
            bf16x8 af = *(const bf16x8*)(arow + k0 * 32 + quad * 8);
            #pragma unroll
            for (int nt = 0; nt < 8; nt++) {
                bf16x8 bf = *(const bf16x8*)(wk + (size_t)(nt * 16 + col) * H_ + k0 * 32 + quad * 8);
                acc[nt] = __builtin_amdgcn_mfma_f32_16x16x32_bf16(af, bf, acc[nt], 0, 0, 0);
            }
        }
        #pragma unroll
        for (int nt = 0; nt < 8; nt++) {
            float bias = bp[(size_t)(k - 1) * P_ + nt * 16 + col];
            #pragma unroll
            for (int r = 0; r < 4; r++)
                Pst[w * 16 + quad * 4 + r][nt * 16 + col] = f2bf(acc[nt][r] + bias);
        }
    }
    __syncthreads();

    // ---- phase 2: flash LSE -------------------------------------------------
    float mloc[4], sloc[4];
    #pragma unroll
    for (int r = 0; r < 4; r++) { mloc[r] = -INFINITY; sloc[r] = 0.f; }

    for (int ct = 0; ct < Tk; ct += 64) {
        f32x4 acc[4] = {};
        #pragma unroll
        for (int k0 = 0; k0 < 4; k0++) {
            bf16x8 af = *(const bf16x8*)(&Pst[w * 16 + col][k0 * 32 + quad * 8]);
            #pragma unroll
            for (int nt = 0; nt < 4; nt++) {
                int tcol = k + ct + nt * 16 + col;   // may over-read into zsum slack (masked)
                bf16x8 bf = *(const bf16x8*)(zb + (size_t)tcol * P_ + k0 * 32 + quad * 8);
                acc[nt] = __builtin_amdgcn_mfma_f32_16x16x32_bf16(af, bf, acc[nt], 0, 0, 0);
            }
        }
        #pragma unroll
        for (int r = 0; r < 4; r++) {
            float l[4];
            float tmax = -INFINITY;
            #pragma unroll
            for (int nt = 0; nt < 4; nt++) {
                bool valid = (ct + nt * 16 + col) < Tk;
                l[nt] = valid ? acc[nt][r] * INV_TEMP : -INFINITY;
                tmax = fmaxf(tmax, l[nt]);
            }
            float mnew = fmaxf(mloc[r], tmax);
            float e = __expf(l[0] - mnew) + __expf(l[1] - mnew)
                    + __expf(l[2] - mnew) + __expf(l[3] - mnew);
            sloc[r] = sloc[r] * __expf(mloc[r] - mnew) + e;
            mloc[r] = mnew;
        }
    }
    #pragma unroll
    for (int r = 0; r < 4; r++) {
        #pragma unroll
        for (int o = 1; o < 16; o <<= 1) {
            float mo = __shfl_xor(mloc[r], o, 64);
            float so = __shfl_xor(sloc[r], o, 64);
            float mn = fmaxf(mloc[r], mo);
            sloc[r] = sloc[r] * __expf(mloc[r] - mn) + so * __expf(mo - mn);
            mloc[r] = mn;
        }
    }
    // mean(logits) per row = (INV_TEMP/Tk) * dot(Pst[row], S)
    float tkinv = INV_TEMP / (float)Tk;
    float scale = 1.0f / ((float)K_ * (float)B_ * (float)Tk);
    float bs = 0.f;
    #pragma unroll
    for (int r = 0; r < 4; r++) {
        int row = w * 16 + quad * 4 + r;
        BF8 pv;
        pv.v = *(const bf16x8*)(&Pst[row][col * 8]);
        float d = 0.f;
        #pragma unroll
        for (int m = 0; m < 8; m++) d = fmaf(bf2f(pv.e[m]), sS[col * 8 + m], d);
        #pragma unroll
        for (int o = 1; o < 16; o <<= 1) d += __shfl_xor(d, o, 64);
        int gr = t0 + row;
        if (gr < Tk) bs += mloc[r] + __logf(sloc[r]) - d * tkinv;
    }
    if (col != 0) bs = 0.f;
    bs = wave_sum(bs);
    if (lane == 0) red[w] = bs;
    __syncthreads();
    if (tid == 0)
        atomicAdd(&accum[(blockIdx.x * 809 + b * 67 + blockIdx.z * 131) & 1023],
                  (red[0] + red[1] + red[2] + red[3]) * scale);
}

__global__ void finalize(const float* __restrict__ accum, float* __restrict__ out) {
    int tid = threadIdx.x;
    __shared__ float red[4];
    float v = 0.f;
    for (int i = tid; i < 1024; i += 256) v += accum[i];
    float sres = wave_sum(v);
    if ((tid & 63) == 0) red[tid >> 6] = sres;
    __syncthreads();
    if (tid == 0) out[0] = red[0] + red[1] + red[2] + red[3];
}

// ---------------- launch -----------------------------------------------------
extern "C" void kernel_launch(void* const* d_in, const int* in_sizes, int n_in,
                              void* d_out, int out_size, void* d_ws, size_t ws_size,
                              hipStream_t stream) {
    const float* x      = (const float*)d_in[0];
    const float* W_enc  = (const float*)d_in[1];
    const float* b_enc  = (const float*)d_in[2];
    const float* W_proj = (const float*)d_in[3];
    const float* b_proj = (const float*)d_in[4];
    const float* Wi     = (const float*)d_in[5];
    const float* bi     = (const float*)d_in[6];
    const float* Wh     = (const float*)d_in[7];
    const float* bhn    = (const float*)d_in[8];
    const float* Wp     = (const float*)d_in[9];
    const float* bp     = (const float*)d_in[10];
    float* out = (float*)d_out;

    // layout (float offsets)
    float* ws    = (float*)d_ws;
    float* bc    = ws;                          // 128
    float* accum = bc + 128;                    // 1024 -> end 1152
    uint2* Whh   = (uint2*)(ws + 1152);         // 98304 fl -> end 99456
    u16* Wct     = (u16*)(ws + 99456);          // 16384 fl -> end 115840
    u16* Wit     = (u16*)(ws + 115840);         // 49152 fl -> end 164992
    u16* Wpt     = (u16*)(ws + 164992);         // 196608 fl -> end 361600
    u16* zh      = (u16*)(ws + 361600);         // 2097152 fl -> end 2458752
    float* zsum  = ws + 2458752;                // 8192 fl (doubles as zh over-read slack) -> end 2466944
    u16* gi      = (u16*)(ws + 2466944);        // 12582912 fl -> end 15049856
    u16* ch      = (u16*)(ws + 15049856);       // 4194304 fl -> end 19244160 (~77 MB)

    const int MT = B_ * T_;                     // 32768

    fold_kernel<<<F_ + 2, P_, 0, stream>>>(W_enc, b_enc, W_proj, b_proj, Wct, bc, accum);
    setup_conv<<<672, 256, 0, stream>>>(Wh, Whh, Wi, Wit, Wp, Wpt);
    // zh = bf16(x @ Wct^T + bc)   (M=32768, N=128, K=256; A converted in-reg)
    gemm_mfma_f32a<<<dim3(1, MT / 64), 256, 0, stream>>>(x, Wct, bc, zh, P_, F_);
    // gi = bf16(zh @ Wit^T + bi)  (M=32768, N=768, K=128)
    gemm_mfma<<<dim3(6, MT / 64), 256, 0, stream>>>(zh, Wit, bi, gi, 3 * H_, P_);
    // parallel column sums of z (for the mean-logit term)
    zsum_kernel<<<B_, 512, 0, stream>>>(zh, zsum);
    // GRU scan -> ch (bf16)
    gru_kernel<<<B_, 512, 0, stream>>>(gi, Whh, bhn, ch);
    // fused pred-GEMM + flash loss (MFMA), all k in one dispatch
    loss_fused<<<dim3(8, B_, K_), 256, 0, stream>>>(ch, Wpt, bp, zh, zsum, accum);
    finalize<<<1, 256, 0, stream>>>(accum, out);
}